// Round 3
// baseline (357.527 us; speedup 1.0000x reference)
//
#include <hip/hip_runtime.h>

// TopologicalDecoder: B=262144 samples, L=16, H=64, C=8, O=32.
// Inputs (float32): z_geo[B,16], z_tex[B,16], chart_w[8,64,16], chart_b[8,64],
// router_w[8,16], router_b[8], centers[8,16], tex_w[64,16], tex_b[64],
// ln_g[64], ln_b[64], w1[64,64], b1[64], w2[32,64], b2[32].
// Output (float32): x_hat[B,32] then router_weights[B,8], concatenated flat.

// LDS layout (floats). Total 16320 floats = 65280 B (< 64 KiB/block limit).
// router_b, b1, b2 are read from global (uniform, L1-cached) to stay under 64K.
constexpr int CW  = 0;      // chart_w  [c][h][l]  8192
constexpr int CB  = 8192;   // chart_b  [c][h]     512
constexpr int TXW = 8704;   // tex_w    [h][l]     1024
constexpr int W1O = 9728;   // w1       [j][k]     4096
constexpr int W2O = 13824;  // w2       [o][j]     2048
constexpr int CEN = 15872;  // centers  [c][l]     128
constexpr int RWO = 16000;  // router_w [c][l]     128
constexpr int TXB = 16128;  // tex_b    [h]        64
constexpr int LNG = 16192;  // ln_g     [h]        64
constexpr int LNB = 16256;  // ln_b     [h]        64
constexpr int LDS_FLOATS = 16320;

__device__ __forceinline__ float gelu_exact(float x) {
    return 0.5f * x * (1.0f + erff(x * 0.7071067811865475f));
}

__global__ __launch_bounds__(256, 2) void topo_decoder(
    const float* __restrict__ zg,  const float* __restrict__ ztx,
    const float* __restrict__ cw,  const float* __restrict__ cb,
    const float* __restrict__ rw,  const float* __restrict__ rb,
    const float* __restrict__ cen, const float* __restrict__ txw,
    const float* __restrict__ txb, const float* __restrict__ lng,
    const float* __restrict__ lnb, const float* __restrict__ w1,
    const float* __restrict__ b1,  const float* __restrict__ w2,
    const float* __restrict__ b2,
    float* __restrict__ out, int B)
{
    __shared__ float s[LDS_FLOATS];
    const int tid = threadIdx.x;

    // ---- stage all weights into LDS (coalesced f32 copies) ----
    for (int i = tid; i < 8192; i += 256) s[CW  + i] = cw[i];
    for (int i = tid; i < 512;  i += 256) s[CB  + i] = cb[i];
    for (int i = tid; i < 1024; i += 256) s[TXW + i] = txw[i];
    for (int i = tid; i < 4096; i += 256) s[W1O + i] = w1[i];
    for (int i = tid; i < 2048; i += 256) s[W2O + i] = w2[i];
    if (tid < 128) s[CEN + tid] = cen[tid];
    if (tid < 128) s[RWO + tid] = rw[tid];
    if (tid < 64)  s[TXB + tid] = txb[tid];
    if (tid < 64)  s[LNG + tid] = lng[tid];
    if (tid < 64)  s[LNB + tid] = lnb[tid];
    __syncthreads();

    const int b = blockIdx.x * 256 + tid;
    if (b >= B) return;

    // ---- load z_geo, z_tex (16 f32 each = 4x float4) ----
    float z[16], zt[16];
    {
        const float4* pg = reinterpret_cast<const float4*>(zg + (size_t)b * 16);
        const float4* pt = reinterpret_cast<const float4*>(ztx + (size_t)b * 16);
        #pragma unroll
        for (int v = 0; v < 4; v++) {
            float4 a = pg[v];
            z[v * 4 + 0] = a.x; z[v * 4 + 1] = a.y; z[v * 4 + 2] = a.z; z[v * 4 + 3] = a.w;
            float4 t = pt[v];
            zt[v * 4 + 0] = t.x; zt[v * 4 + 1] = t.y; zt[v * 4 + 2] = t.z; zt[v * 4 + 3] = t.w;
        }
    }

    // ---- router scores ----
    float r2 = 0.f;
    #pragma unroll
    for (int l = 0; l < 16; l++) r2 = fmaf(z[l], z[l], r2);
    const float tau = fmaxf(2.0f * fmaxf(1.0f - r2, 0.001f), 0.01f); // sqrt(16)*0.5 = 2
    const float inv_tau = 1.0f / tau;

    float scv[8];
    float smax = -1e30f;
    #pragma unroll
    for (int c = 0; c < 8; c++) {
        float dsq = 0.f, csq = 0.f, dotv = 0.f;
        #pragma unroll
        for (int l = 0; l < 16; l++) {
            float cv = s[CEN + c * 16 + l];
            float d  = z[l] - cv;
            dsq  = fmaf(d, d, dsq);
            csq  = fmaf(cv, cv, csq);
            dotv = fmaf(z[l], s[RWO + c * 16 + l], dotv);
        }
        float denom = (1.0f - r2) * (1.0f - csq);
        float arg   = 1.0f + 2.0f * dsq / (denom + 0.001f);
        float dist  = acoshf(fmaxf(arg, 1.001f));
        float score = (-dist + 0.1f * (dotv + rb[c])) * inv_tau;
        scv[c] = score;
        smax = fmaxf(smax, score);
    }
    float esum = 0.f;
    #pragma unroll
    for (int c = 0; c < 8; c++) { scv[c] = __expf(scv[c] - smax); esum += scv[c]; }
    const float rinv = 1.0f / esum;
    #pragma unroll
    for (int c = 0; c < 8; c++) scv[c] *= rinv;

    // ---- router_weights out: 8 f32 = 2x float4 ----
    {
        float4* pr = reinterpret_cast<float4*>(out + (size_t)B * 32 + (size_t)b * 8);
        pr[0] = make_float4(scv[0], scv[1], scv[2], scv[3]);
        pr[1] = make_float4(scv[4], scv[5], scv[6], scv[7]);
    }

    // ---- h = tex_b + z_tex @ tex_w^T + sum_c rw_c * (chart_w[c] @ z + chart_b[c]) ----
    float h[64];
    #pragma unroll
    for (int hh = 0; hh < 64; hh++) {
        float a = s[TXB + hh];
        #pragma unroll
        for (int l = 0; l < 16; l++) a = fmaf(s[TXW + hh * 16 + l], zt[l], a);
        h[hh] = a;
    }
    for (int c = 0; c < 8; c++) {  // dynamic: keeps code size bounded
        const float wc = scv[c];
        const float* Wc = &s[CW + c * 1024];
        const float* Bc = &s[CB + c * 64];
        #pragma unroll
        for (int hh = 0; hh < 64; hh++) {
            float d = Bc[hh];
            #pragma unroll
            for (int l = 0; l < 16; l++) d = fmaf(Wc[hh * 16 + l], z[l], d);
            h[hh] = fmaf(wc, d, h[hh]);
        }
    }

    // ---- LayerNorm -> GELU ----
    float mu = 0.f;
    #pragma unroll
    for (int hh = 0; hh < 64; hh++) mu += h[hh];
    mu *= (1.0f / 64.0f);
    float var = 0.f;
    #pragma unroll
    for (int hh = 0; hh < 64; hh++) { float d = h[hh] - mu; var = fmaf(d, d, var); }
    var *= (1.0f / 64.0f);
    const float rs = rsqrtf(var + 1e-5f);
    float g1[64];
    #pragma unroll
    for (int hh = 0; hh < 64; hh++) {
        float hn = (h[hh] - mu) * rs * s[LNG + hh] + s[LNB + hh];
        g1[hh] = gelu_exact(hn);
    }

    // ---- h1 = gelu(g1 @ w1^T + b1) ----
    float h1[64];
    #pragma unroll
    for (int j = 0; j < 64; j++) {
        float a = b1[j];
        #pragma unroll
        for (int k = 0; k < 64; k++) a = fmaf(g1[k], s[W1O + j * 64 + k], a);
        h1[j] = gelu_exact(a);
    }

    // ---- x_hat = h1 @ w2^T + b2 ----
    float4* po = reinterpret_cast<float4*>(out + (size_t)b * 32);
    #pragma unroll
    for (int o4 = 0; o4 < 8; o4++) {
        float acc[4];
        #pragma unroll
        for (int u = 0; u < 4; u++) {
            int o = o4 * 4 + u;
            float a = b2[o];
            #pragma unroll
            for (int j = 0; j < 64; j++) a = fmaf(h1[j], s[W2O + o * 64 + j], a);
            acc[u] = a;
        }
        po[o4] = make_float4(acc[0], acc[1], acc[2], acc[3]);
    }
}

extern "C" void kernel_launch(void* const* d_in, const int* in_sizes, int n_in,
                              void* d_out, int out_size, void* d_ws, size_t ws_size,
                              hipStream_t stream) {
    const int B = in_sizes[0] / 16;
    dim3 grid((B + 255) / 256), block(256);
    hipLaunchKernelGGL(topo_decoder, grid, block, 0, stream,
        (const float*)d_in[0],  (const float*)d_in[1],
        (const float*)d_in[2],  (const float*)d_in[3],
        (const float*)d_in[4],  (const float*)d_in[5],
        (const float*)d_in[6],  (const float*)d_in[7],
        (const float*)d_in[8],  (const float*)d_in[9],
        (const float*)d_in[10], (const float*)d_in[11],
        (const float*)d_in[12], (const float*)d_in[13],
        (const float*)d_in[14],
        (float*)d_out, B);
}